// Round 4
// baseline (1262.336 us; speedup 1.0000x reference)
//
#include <hip/hip_runtime.h>
#include <cstdint>
#include <cstddef>

#define NN 50000      // nodes
#define NE 800000     // edges
#define DF 128        // feature dim
#define HF 256        // hidden dim
#define NR 4          // dropout runs
#define NB1 196       // ceil(NN/256)

// workspace layout
//  S        [NN][DF]  f32   unmasked in-edge sum
//  C        [NR][NN][DF] f32 dropped-src correction (agg_r = S - C_r)
//  deg      [NN] i32
//  rowstart [NN] i32
//  cursor   [NN] i32
//  bsum/boff[256] i32 each
//  adj      [NE] i32  (src node id per CSR slot)
//  flag     [1]  i32  drop-mask dtype detect (1 = byte-bool, 0 = int32)
//  bits     [NN] u8   packed drop mask over 4 runs
static const size_t C_OFF   = (size_t)NN * DF;
static const size_t INT_OFF = C_OFF + (size_t)NR * NN * DF;   // floats before int region

__global__ __launch_bounds__(256) void k_zero_deg(int* __restrict__ deg, int* __restrict__ flag) {
  int n = blockIdx.x * 256 + threadIdx.x;
  if (n < NN) deg[n] = 0;
  if (n == 0) *flag = 0;
}

// If drop_mask is int32 {0,1}, all bytes at idx%4!=0 are zero. If it is
// 1-byte bool, ~7.5k of the first 200000 such bytes are nonzero.
__global__ __launch_bounds__(256) void k_detect(const unsigned char* __restrict__ dropb,
                                                int* __restrict__ flag) {
  int i = blockIdx.x * 256 + threadIdx.x;   // over NR*NN bytes (safe for both dtypes)
  if (i < NR * NN && (i & 3) != 0 && dropb[i] != 0) atomicOr(flag, 1);
}

__global__ __launch_bounds__(256) void k_pack(const unsigned char* __restrict__ dropb,
                                              const int* __restrict__ dropi,
                                              const int* __restrict__ flag,
                                              unsigned char* __restrict__ bits) {
  int n = blockIdx.x * 256 + threadIdx.x;
  if (n < NN) {
    const int byte_mode = *flag;
    unsigned b = 0;
#pragma unroll
    for (int r = 0; r < NR; ++r) {
      int v = byte_mode ? (int)dropb[(size_t)r * NN + n] : dropi[(size_t)r * NN + n];
      b |= (v != 0 ? 1u : 0u) << r;
    }
    bits[n] = (unsigned char)b;
  }
}

__global__ __launch_bounds__(256) void k_hist(const int* __restrict__ ei, int* __restrict__ deg) {
  int e = blockIdx.x * 256 + threadIdx.x;
  if (e < NE) atomicAdd(&deg[ei[NE + e]], 1);
}

__global__ __launch_bounds__(256) void k_scan1(const int* __restrict__ deg,
    int* __restrict__ rowstart, int* __restrict__ bsum) {
  __shared__ int s[256];
  int t = threadIdx.x, n = blockIdx.x * 256 + t;
  int v = (n < NN) ? deg[n] : 0;
  s[t] = v; __syncthreads();
  for (int off = 1; off < 256; off <<= 1) {
    int a = s[t]; int b = (t >= off) ? s[t - off] : 0;
    __syncthreads(); s[t] = a + b; __syncthreads();
  }
  if (n < NN) rowstart[n] = s[t] - v;
  if (t == 255) bsum[blockIdx.x] = s[255];
}

__global__ __launch_bounds__(256) void k_scan2(const int* __restrict__ bsum, int* __restrict__ boff) {
  __shared__ int s[256];
  int t = threadIdx.x;
  int v = (t < NB1) ? bsum[t] : 0;
  s[t] = v; __syncthreads();
  for (int off = 1; off < 256; off <<= 1) {
    int a = s[t]; int b = (t >= off) ? s[t - off] : 0;
    __syncthreads(); s[t] = a + b; __syncthreads();
  }
  if (t < NB1) boff[t] = s[t] - v;
}

__global__ __launch_bounds__(256) void k_scan3(int* __restrict__ rowstart,
    const int* __restrict__ boff, int* __restrict__ cursor) {
  int n = blockIdx.x * 256 + threadIdx.x;
  if (n < NN) {
    int rs = rowstart[n] + boff[blockIdx.x];
    rowstart[n] = rs;
    cursor[n] = rs;
  }
}

__global__ __launch_bounds__(256) void k_fill(const int* __restrict__ ei,
    int* __restrict__ cursor, int* __restrict__ adj) {
  int e = blockIdx.x * 256 + threadIdx.x;
  if (e < NE) {
    int src = ei[e], dst = ei[NE + e];
    int pos = atomicAdd(&cursor[dst], 1);
    adj[pos] = src;
  }
}

// One node per 32 threads (8 nodes/block). Sum incoming src rows; correction
// accumulators per run only for dropped srcs. No fp32 atomics anywhere.
__global__ __launch_bounds__(256) void k_gather(const float* __restrict__ x,
    const int* __restrict__ adj, const int* __restrict__ rowstart,
    const int* __restrict__ deg, const unsigned char* __restrict__ bits,
    float* __restrict__ S, float* __restrict__ C) {
  const int n  = blockIdx.x * 8 + (threadIdx.x >> 5);
  const int d4 = (threadIdx.x & 31) * 4;
  const int start = rowstart[n], dg = deg[n];
  float4 aS = make_float4(0.f, 0.f, 0.f, 0.f);
  float4 aC[NR];
#pragma unroll
  for (int r = 0; r < NR; ++r) aC[r] = make_float4(0.f, 0.f, 0.f, 0.f);

  int i = 0;
  for (; i + 2 <= dg; i += 2) {
    int s0 = adj[start + i], s1 = adj[start + i + 1];
    const float4 v0 = *(const float4*)&x[(size_t)s0 * DF + d4];
    const float4 v1 = *(const float4*)&x[(size_t)s1 * DF + d4];
    unsigned b0 = bits[s0], b1 = bits[s1];
    aS.x += v0.x + v1.x; aS.y += v0.y + v1.y;
    aS.z += v0.z + v1.z; aS.w += v0.w + v1.w;
#pragma unroll
    for (int r = 0; r < NR; ++r) {
      if (b0 & (1u << r)) { aC[r].x += v0.x; aC[r].y += v0.y; aC[r].z += v0.z; aC[r].w += v0.w; }
      if (b1 & (1u << r)) { aC[r].x += v1.x; aC[r].y += v1.y; aC[r].z += v1.z; aC[r].w += v1.w; }
    }
  }
  if (i < dg) {
    int s0 = adj[start + i];
    const float4 v0 = *(const float4*)&x[(size_t)s0 * DF + d4];
    unsigned b0 = bits[s0];
    aS.x += v0.x; aS.y += v0.y; aS.z += v0.z; aS.w += v0.w;
#pragma unroll
    for (int r = 0; r < NR; ++r)
      if (b0 & (1u << r)) { aC[r].x += v0.x; aC[r].y += v0.y; aC[r].z += v0.z; aC[r].w += v0.w; }
  }

  *(float4*)&S[(size_t)n * DF + d4] = aS;
#pragma unroll
  for (int r = 0; r < NR; ++r)
    *(float4*)&C[((size_t)r * NN + n) * DF + d4] = aC[r];
}

__device__ __forceinline__ float mishf(float z) {
  float sp = (z > 20.f) ? z : log1pf(expf(z));   // jax.nn.softplus
  return z * tanhf(sp);
}

// Fused MLP: rows = node*4+run, 64 rows/block (16 nodes x 4 runs), 256 threads.
// Phase 1: acc1[8][8] = H @ W1 (k=128).  Phase 2 (per 128-col half): mish ->
// swizzled As in LDS, acc2[4][8] += As @ W2.  Run-mean + residual in epilogue.
__global__ __launch_bounds__(256) void k_mlp12(const float* __restrict__ x,
    const float* __restrict__ S, const float* __restrict__ C,
    const unsigned char* __restrict__ bits,
    const float* __restrict__ W1, const float* __restrict__ b1,
    const float* __restrict__ W2, const float* __restrict__ b2,
    float* __restrict__ out) {
  __shared__ float sm[16384];      // 64 KB, aliased across phases
  float* Hs  = sm;                 // [64][128]  phase 1
  float* Ws1 = sm + 8192;          // [32][256]  phase 1
  float* As  = sm;                 // [64][128]  phase 2, XOR-swizzled
  float* Ws2 = sm + 8192;          // [32][128]  phase 2

  const int tid  = threadIdx.x;
  const int row0 = blockIdx.x * 64;

  // stage H = S - C_r + (kept ? x : 0)
  for (int i = tid; i < 2048; i += 256) {
    int row = i >> 5, d4 = (i & 31) * 4;
    int gr = row0 + row, n = gr >> 2, r = gr & 3;
    const float4 s4 = *(const float4*)&S[(size_t)n * DF + d4];
    const float4 c4 = *(const float4*)&C[((size_t)r * NN + n) * DF + d4];
    float4 h4 = make_float4(s4.x - c4.x, s4.y - c4.y, s4.z - c4.z, s4.w - c4.w);
    if (!((bits[n] >> r) & 1)) {
      const float4 x4 = *(const float4*)&x[(size_t)n * DF + d4];
      h4.x += x4.x; h4.y += x4.y; h4.z += x4.z; h4.w += x4.w;
    }
    *(float4*)&Hs[row * DF + d4] = h4;
  }

  const int cg = tid & 31, rg = tid >> 5;   // phase-1: rows rg*8+rr, cols cg+32*jj
  float acc1[8][8];
#pragma unroll
  for (int a = 0; a < 8; ++a)
#pragma unroll
    for (int b = 0; b < 8; ++b) acc1[a][b] = 0.f;

  for (int kc = 0; kc < DF; kc += 32) {
    __syncthreads();
    for (int i = tid; i < 2048; i += 256) {
      int k = i >> 6, c4 = (i & 63) * 4;
      *(float4*)&Ws1[k * HF + c4] = *(const float4*)&W1[(size_t)(kc + k) * HF + c4];
    }
    __syncthreads();
#pragma unroll
    for (int k = 0; k < 32; ++k) {
      float w[8], h[8];
#pragma unroll
      for (int jj = 0; jj < 8; ++jj) w[jj] = Ws1[k * HF + cg + 32 * jj];
#pragma unroll
      for (int rr = 0; rr < 8; ++rr) h[rr] = Hs[(rg * 8 + rr) * DF + kc + k];
#pragma unroll
      for (int rr = 0; rr < 8; ++rr)
#pragma unroll
        for (int jj = 0; jj < 8; ++jj) acc1[rr][jj] = fmaf(h[rr], w[jj], acc1[rr][jj]);
    }
  }

  const int cg2 = tid & 15, rg2 = tid >> 4; // phase-2: node rg2, cols cg2+16*jj
  float acc2[4][8];
#pragma unroll
  for (int a = 0; a < 4; ++a)
#pragma unroll
    for (int b = 0; b < 8; ++b) acc2[a][b] = 0.f;

#pragma unroll
  for (int hh = 0; hh < 2; ++hh) {          // hidden halves [0,128), [128,256)
    __syncthreads();                         // all reads of previous contents done
#pragma unroll
    for (int jj = 4 * hh; jj < 4 * hh + 4; ++jj) {
      int col = cg + 32 * jj;               // global hidden col
      int kloc = col - hh * 128;
      float bb = b1[col];
#pragma unroll
      for (int rr = 0; rr < 8; ++rr) {
        int row = rg * 8 + rr;
        As[row * 128 + (kloc ^ (((row >> 2) & 3) << 3))] = mishf(acc1[rr][jj] + bb);
      }
    }
    for (int kc = 0; kc < 128; kc += 32) {
      __syncthreads();
      for (int i = tid; i < 1024; i += 256) {
        int k = i >> 5, c4 = (i & 31) * 4;
        *(float4*)&Ws2[k * DF + c4] =
            *(const float4*)&W2[(size_t)(hh * 128 + kc + k) * DF + c4];
      }
      __syncthreads();
#pragma unroll
      for (int k = 0; k < 32; ++k) {
        float w[8], a[4];
#pragma unroll
        for (int jj = 0; jj < 8; ++jj) w[jj] = Ws2[k * DF + cg2 + 16 * jj];
#pragma unroll
        for (int rr = 0; rr < 4; ++rr) {
          int row = rg2 * 4 + rr;
          a[rr] = As[row * 128 + ((kc + k) ^ (((row >> 2) & 3) << 3))];
        }
#pragma unroll
        for (int rr = 0; rr < 4; ++rr)
#pragma unroll
          for (int jj = 0; jj < 8; ++jj) acc2[rr][jj] = fmaf(a[rr], w[jj], acc2[rr][jj]);
      }
    }
  }

  const int n = (row0 >> 2) + rg2;
#pragma unroll
  for (int jj = 0; jj < 8; ++jj) {
    int j = cg2 + 16 * jj;
    out[(size_t)n * DF + j] = b2[j]
        + 0.25f * (acc2[0][jj] + acc2[1][jj] + acc2[2][jj] + acc2[3][jj])
        + x[(size_t)n * DF + j];
  }
}

extern "C" void kernel_launch(void* const* d_in, const int* in_sizes, int n_in,
                              void* d_out, int out_size, void* d_ws, size_t ws_size,
                              hipStream_t stream) {
  const float* x             = (const float*)d_in[0];
  const int* ei              = (const int*)d_in[1];
  const unsigned char* dropb = (const unsigned char*)d_in[2];
  const int* dropi           = (const int*)d_in[2];
  const float* W1            = (const float*)d_in[3];
  const float* b1            = (const float*)d_in[4];
  const float* W2            = (const float*)d_in[5];
  const float* b2            = (const float*)d_in[6];
  float* out = (float*)d_out;

  float* ws = (float*)d_ws;
  float* S  = ws;
  float* C  = ws + C_OFF;
  int* deg      = (int*)(ws + INT_OFF);
  int* rowstart = deg + NN;
  int* cursor   = rowstart + NN;
  int* bsum     = cursor + NN;
  int* boff     = bsum + 256;
  int* adj      = boff + 256;
  int* flag     = adj + NE;
  unsigned char* bits = (unsigned char*)(flag + 1);

  k_zero_deg<<<NB1, 256, 0, stream>>>(deg, flag);
  k_detect<<<(NR * NN + 255) / 256, 256, 0, stream>>>(dropb, flag);
  k_pack<<<NB1, 256, 0, stream>>>(dropb, dropi, flag, bits);
  k_hist<<<(NE + 255) / 256, 256, 0, stream>>>(ei, deg);
  k_scan1<<<NB1, 256, 0, stream>>>(deg, rowstart, bsum);
  k_scan2<<<1, 256, 0, stream>>>(bsum, boff);
  k_scan3<<<NB1, 256, 0, stream>>>(rowstart, boff, cursor);
  k_fill<<<(NE + 255) / 256, 256, 0, stream>>>(ei, cursor, adj);
  k_gather<<<NN / 8, 256, 0, stream>>>(x, adj, rowstart, deg, bits, S, C);
  k_mlp12<<<(NR * NN) / 64, 256, 0, stream>>>(x, S, C, bits, W1, b1, W2, b2, out);
}

// Round 5
// 315.787 us; speedup vs baseline: 3.9974x; 3.9974x over previous
//
#include <hip/hip_runtime.h>
#include <cstdint>
#include <cstddef>

#define NN 50000      // nodes
#define NE 800000     // edges
#define DF 128        // feature dim
#define HF 256        // hidden dim
#define NR 4          // dropout runs
#define NB1 196       // ceil(NN/256)

typedef __attribute__((ext_vector_type(8))) short short8;      // 8 bf16 = 4 VGPR
typedef __attribute__((ext_vector_type(4))) float f32x4;       // MFMA C/D
typedef __attribute__((ext_vector_type(4))) unsigned short ushort4v;

// workspace layout (bytes):
//  H    [NR*NN][DF] bf16 (row = n*4+r)   51,200,000
//  W1T  [HF][DF]   bf16 (W1 transposed)      65,536
//  W2T  [DF][HF]   bf16 (W2 transposed)      65,536
//  ints deg/rowstart/cursor/bsum/boff/adj/flag
//  bits [NN] u8 packed drop mask
static const size_t H_BYTES = (size_t)NR * NN * DF * 2;
static const size_t W1T_OFF = H_BYTES;
static const size_t W2T_OFF = W1T_OFF + (size_t)DF * HF * 2;
static const size_t INT_OFF = W2T_OFF + (size_t)DF * HF * 2;

__device__ __forceinline__ unsigned short f2bf(float f) {   // RNE fp32->bf16
  union { float f; unsigned u; } v; v.f = f;
  unsigned r = v.u + 0x7FFF + ((v.u >> 16) & 1);
  return (unsigned short)(r >> 16);
}

__device__ __forceinline__ float mishf(float z) {
  // mish(z) = z*tanh(softplus(z)) = z*((1+e^z)^2-1)/((1+e^z)^2+1)
  float t = __expf(z);
  float u = fmaf(t, t + 2.f, 1.f);        // (1+t)^2
  float m = z * (u - 1.f) / (u + 1.f);
  return (z > 30.f) ? z : m;              // large z: tanh(..)==1; avoids inf/inf
}

__global__ __launch_bounds__(256) void k_zero_deg(int* __restrict__ deg, int* __restrict__ flag) {
  int n = blockIdx.x * 256 + threadIdx.x;
  if (n < NN) deg[n] = 0;
  if (n == 0) *flag = 0;
}

// drop_mask dtype detect: int32 {0,1} -> bytes at i%4!=0 all zero; byte-bool -> many nonzero.
__global__ __launch_bounds__(256) void k_detect(const unsigned char* __restrict__ dropb,
                                                int* __restrict__ flag) {
  int i = blockIdx.x * 256 + threadIdx.x;
  if (i < NR * NN && (i & 3) != 0 && dropb[i] != 0) atomicOr(flag, 1);
}

__global__ __launch_bounds__(256) void k_pack(const unsigned char* __restrict__ dropb,
                                              const int* __restrict__ dropi,
                                              const int* __restrict__ flag,
                                              unsigned char* __restrict__ bits) {
  int n = blockIdx.x * 256 + threadIdx.x;
  if (n < NN) {
    const int byte_mode = *flag;
    unsigned b = 0;
#pragma unroll
    for (int r = 0; r < NR; ++r) {
      int v = byte_mode ? (int)dropb[(size_t)r * NN + n] : dropi[(size_t)r * NN + n];
      b |= (v != 0 ? 1u : 0u) << r;
    }
    bits[n] = (unsigned char)b;
  }
}

__global__ __launch_bounds__(256) void k_hist(const int* __restrict__ ei, int* __restrict__ deg) {
  int e = blockIdx.x * 256 + threadIdx.x;
  if (e < NE) atomicAdd(&deg[ei[NE + e]], 1);
}

__global__ __launch_bounds__(256) void k_scan1(const int* __restrict__ deg,
    int* __restrict__ rowstart, int* __restrict__ bsum) {
  __shared__ int s[256];
  int t = threadIdx.x, n = blockIdx.x * 256 + t;
  int v = (n < NN) ? deg[n] : 0;
  s[t] = v; __syncthreads();
  for (int off = 1; off < 256; off <<= 1) {
    int a = s[t]; int b = (t >= off) ? s[t - off] : 0;
    __syncthreads(); s[t] = a + b; __syncthreads();
  }
  if (n < NN) rowstart[n] = s[t] - v;
  if (t == 255) bsum[blockIdx.x] = s[255];
}

__global__ __launch_bounds__(256) void k_scan2(const int* __restrict__ bsum, int* __restrict__ boff) {
  __shared__ int s[256];
  int t = threadIdx.x;
  int v = (t < NB1) ? bsum[t] : 0;
  s[t] = v; __syncthreads();
  for (int off = 1; off < 256; off <<= 1) {
    int a = s[t]; int b = (t >= off) ? s[t - off] : 0;
    __syncthreads(); s[t] = a + b; __syncthreads();
  }
  if (t < NB1) boff[t] = s[t] - v;
}

__global__ __launch_bounds__(256) void k_scan3(int* __restrict__ rowstart,
    const int* __restrict__ boff, int* __restrict__ cursor) {
  int n = blockIdx.x * 256 + threadIdx.x;
  if (n < NN) {
    int rs = rowstart[n] + boff[blockIdx.x];
    rowstart[n] = rs;
    cursor[n] = rs;
  }
}

__global__ __launch_bounds__(256) void k_fill(const int* __restrict__ ei,
    int* __restrict__ cursor, int* __restrict__ adj) {
  int e = blockIdx.x * 256 + threadIdx.x;
  if (e < NE) {
    int src = ei[e], dst = ei[NE + e];
    int pos = atomicAdd(&cursor[dst], 1);
    adj[pos] = src;
  }
}

// W1T[n][k] = bf16(W1[k][n]) (256x128); W2T[n][k] = bf16(W2[k][n]) (128x256)
__global__ __launch_bounds__(256) void k_wprep(const float* __restrict__ W1,
    const float* __restrict__ W2, unsigned short* __restrict__ W1T,
    unsigned short* __restrict__ W2T) {
  int i = blockIdx.x * 256 + threadIdx.x;           // 0..65535
  if (i < DF * HF) {
    int n = i >> 7, k = i & 127;                    // n<256, k<128
    W1T[i] = f2bf(W1[(size_t)k * HF + n]);
  } else {
    int j = i - DF * HF;
    int n = j >> 8, k = j & 255;                    // n<128, k<256
    W2T[j] = f2bf(W2[(size_t)k * DF + n]);
  }
}

// 32 threads per node: CSR gather of src rows; per-run dropped-src correction;
// writes H[n*4+r] = bf16(S - C_r + kept_r * x_n). No fp32 atomics.
__global__ __launch_bounds__(256) void k_gather(const float* __restrict__ x,
    const int* __restrict__ adj, const int* __restrict__ rowstart,
    const int* __restrict__ deg, const unsigned char* __restrict__ bits,
    unsigned short* __restrict__ H) {
  const int n  = blockIdx.x * 8 + (threadIdx.x >> 5);
  const int d4 = (threadIdx.x & 31) * 4;
  const int start = rowstart[n], dg = deg[n];
  float4 aS = make_float4(0.f, 0.f, 0.f, 0.f);
  float4 aC[NR];
#pragma unroll
  for (int r = 0; r < NR; ++r) aC[r] = make_float4(0.f, 0.f, 0.f, 0.f);

  int i = 0;
  for (; i + 2 <= dg; i += 2) {
    int s0 = adj[start + i], s1 = adj[start + i + 1];
    const float4 v0 = *(const float4*)&x[(size_t)s0 * DF + d4];
    const float4 v1 = *(const float4*)&x[(size_t)s1 * DF + d4];
    unsigned b0 = bits[s0], b1 = bits[s1];
    aS.x += v0.x + v1.x; aS.y += v0.y + v1.y;
    aS.z += v0.z + v1.z; aS.w += v0.w + v1.w;
#pragma unroll
    for (int r = 0; r < NR; ++r) {
      if (b0 & (1u << r)) { aC[r].x += v0.x; aC[r].y += v0.y; aC[r].z += v0.z; aC[r].w += v0.w; }
      if (b1 & (1u << r)) { aC[r].x += v1.x; aC[r].y += v1.y; aC[r].z += v1.z; aC[r].w += v1.w; }
    }
  }
  if (i < dg) {
    int s0 = adj[start + i];
    const float4 v0 = *(const float4*)&x[(size_t)s0 * DF + d4];
    unsigned b0 = bits[s0];
    aS.x += v0.x; aS.y += v0.y; aS.z += v0.z; aS.w += v0.w;
#pragma unroll
    for (int r = 0; r < NR; ++r)
      if (b0 & (1u << r)) { aC[r].x += v0.x; aC[r].y += v0.y; aC[r].z += v0.z; aC[r].w += v0.w; }
  }

  const float4 x4 = *(const float4*)&x[(size_t)n * DF + d4];
  const unsigned bn = bits[n];
#pragma unroll
  for (int r = 0; r < NR; ++r) {
    float hx = aS.x - aC[r].x, hy = aS.y - aC[r].y;
    float hz = aS.z - aC[r].z, hw = aS.w - aC[r].w;
    if (!((bn >> r) & 1)) { hx += x4.x; hy += x4.y; hz += x4.z; hw += x4.w; }
    ushort4v u;
    u.x = f2bf(hx); u.y = f2bf(hy); u.z = f2bf(hz); u.w = f2bf(hw);
    *(ushort4v*)&H[((size_t)(n * NR + r)) * DF + d4] = u;
  }
}

// Fused MFMA MLP. 64 rows/block (16 nodes x 4 runs), 4 waves.
// GEMM1: 64x256x128; mish -> bf16 As (LDS, XOR-16B swizzle); GEMM2: 64x128x256.
// C/D layout (m89): col=lane&15, row=(lane>>4)*4+reg -> each thread's 4 regs
// of a tile are 4 runs of ONE node -> run-mean is in-register.
__global__ __launch_bounds__(256) void k_mlp_mfma(const unsigned short* __restrict__ H,
    const unsigned short* __restrict__ W1T, const unsigned short* __restrict__ W2T,
    const float* __restrict__ b1, const float* __restrict__ b2,
    const float* __restrict__ x, float* __restrict__ out) {
  __shared__ unsigned char lds[49152];
  unsigned char* HsB = lds;            // [64 rows][256 B] swizzled
  unsigned char* AsB = lds + 16384;    // [64 rows][512 B] swizzled

  const int tid = threadIdx.x;
  const int wid = tid >> 6, lane = tid & 63;
  const int lg = lane >> 4, lr = lane & 15;
  const int row0 = blockIdx.x * 64;
  const int swz = (lr & 7) << 4;       // read-side swizzle for rows m*16+lr

  // stage H rows (contiguous 16 KB) into swizzled Hs
  const unsigned char* Hsrc = (const unsigned char*)(H + (size_t)row0 * DF);
#pragma unroll
  for (int c = 0; c < 4; ++c) {
    int q = tid * 4 + c;               // 16B chunk id, 0..1023
    int row = q >> 4, kb = (q & 15) * 16;
    short8 v = *(const short8*)(Hsrc + (size_t)q * 16);
    *(short8*)(HsB + row * 256 + (kb ^ ((row & 7) << 4))) = v;
  }
  __syncthreads();

  // ---- GEMM1: acc1[m][nr], wave cols [wid*64, wid*64+64) ----
  f32x4 acc1[4][4] = {};
#pragma unroll
  for (int ks = 0; ks < 4; ++ks) {
    short8 Af[4];
#pragma unroll
    for (int m = 0; m < 4; ++m)
      Af[m] = *(const short8*)(HsB + (m * 16 + lr) * 256 + ((ks * 64 + lg * 16) ^ swz));
#pragma unroll
    for (int nr = 0; nr < 4; ++nr) {
      int n1 = wid * 64 + nr * 16 + lr;
      short8 Bf = *(const short8*)(W1T + (size_t)n1 * DF + ks * 32 + lg * 8);
#pragma unroll
      for (int m = 0; m < 4; ++m)
        acc1[m][nr] = __builtin_amdgcn_mfma_f32_16x16x32_bf16(Af[m], Bf, acc1[m][nr], 0, 0, 0);
    }
  }

  // ---- bias + mish -> bf16 As ----
#pragma unroll
  for (int nr = 0; nr < 4; ++nr) {
    int col = wid * 64 + nr * 16 + lr;
    float bb = b1[col];
#pragma unroll
    for (int m = 0; m < 4; ++m) {
#pragma unroll
      for (int i = 0; i < 4; ++i) {
        int row = m * 16 + lg * 4 + i;
        float a = mishf(acc1[m][nr][i] + bb);
        *(unsigned short*)(AsB + row * 512 + ((col * 2) ^ ((row & 7) << 4))) = f2bf(a);
      }
    }
  }
  __syncthreads();

  // ---- GEMM2: acc2[m][nr], wave cols [wid*32, wid*32+32) ----
  f32x4 acc2[4][2] = {};
#pragma unroll
  for (int ks = 0; ks < 8; ++ks) {
    short8 Af[4];
#pragma unroll
    for (int m = 0; m < 4; ++m)
      Af[m] = *(const short8*)(AsB + (m * 16 + lr) * 512 + ((ks * 64 + lg * 16) ^ swz));
#pragma unroll
    for (int nr = 0; nr < 2; ++nr) {
      int n2 = wid * 32 + nr * 16 + lr;
      short8 Bf = *(const short8*)(W2T + (size_t)n2 * HF + ks * 32 + lg * 8);
#pragma unroll
      for (int m = 0; m < 4; ++m)
        acc2[m][nr] = __builtin_amdgcn_mfma_f32_16x16x32_bf16(Af[m], Bf, acc2[m][nr], 0, 0, 0);
    }
  }

  // ---- run-mean + bias + residual ----
  const int nodebase = row0 >> 2;
#pragma unroll
  for (int m = 0; m < 4; ++m) {
    int node = nodebase + m * 4 + lg;
#pragma unroll
    for (int nr = 0; nr < 2; ++nr) {
      int col = wid * 32 + nr * 16 + lr;
      float mean = 0.25f * (acc2[m][nr][0] + acc2[m][nr][1] + acc2[m][nr][2] + acc2[m][nr][3]);
      out[(size_t)node * DF + col] = mean + b2[col] + x[(size_t)node * DF + col];
    }
  }
}

extern "C" void kernel_launch(void* const* d_in, const int* in_sizes, int n_in,
                              void* d_out, int out_size, void* d_ws, size_t ws_size,
                              hipStream_t stream) {
  const float* x             = (const float*)d_in[0];
  const int* ei              = (const int*)d_in[1];
  const unsigned char* dropb = (const unsigned char*)d_in[2];
  const int* dropi           = (const int*)d_in[2];
  const float* W1            = (const float*)d_in[3];
  const float* b1            = (const float*)d_in[4];
  const float* W2            = (const float*)d_in[5];
  const float* b2            = (const float*)d_in[6];
  float* out = (float*)d_out;

  unsigned char* wsb = (unsigned char*)d_ws;
  unsigned short* H   = (unsigned short*)wsb;
  unsigned short* W1T = (unsigned short*)(wsb + W1T_OFF);
  unsigned short* W2T = (unsigned short*)(wsb + W2T_OFF);
  int* deg      = (int*)(wsb + INT_OFF);
  int* rowstart = deg + NN;
  int* cursor   = rowstart + NN;
  int* bsum     = cursor + NN;
  int* boff     = bsum + 256;
  int* adj      = boff + 256;
  int* flag     = adj + NE;
  unsigned char* bits = (unsigned char*)(flag + 1);

  k_zero_deg<<<NB1, 256, 0, stream>>>(deg, flag);
  k_detect<<<(NR * NN + 255) / 256, 256, 0, stream>>>(dropb, flag);
  k_pack<<<NB1, 256, 0, stream>>>(dropb, dropi, flag, bits);
  k_hist<<<(NE + 255) / 256, 256, 0, stream>>>(ei, deg);
  k_scan1<<<NB1, 256, 0, stream>>>(deg, rowstart, bsum);
  k_scan2<<<1, 256, 0, stream>>>(bsum, boff);
  k_scan3<<<NB1, 256, 0, stream>>>(rowstart, boff, cursor);
  k_fill<<<(NE + 255) / 256, 256, 0, stream>>>(ei, cursor, adj);
  k_wprep<<<(2 * DF * HF) / 256, 256, 0, stream>>>(W1, W2, W1T, W2T);
  k_gather<<<NN / 8, 256, 0, stream>>>(x, adj, rowstart, deg, bits, H);
  k_mlp_mfma<<<(NR * NN) / 64, 256, 0, stream>>>(H, W1T, W2T, b1, b2, x, out);
}